// Round 9
// baseline (443.024 us; speedup 1.0000x reference)
//
#include <hip/hip_runtime.h>
#include <hip/hip_bf16.h>

#define FDIM 128

typedef __attribute__((ext_vector_type(8))) short short8v;   // 8 bf16 in 4 VGPRs
typedef __attribute__((ext_vector_type(4))) float f32x4;
typedef __attribute__((ext_vector_type(4))) unsigned uint4v;

__device__ __forceinline__ short f2bf(float f) {             // RNE f32 -> bf16 bits
    unsigned u = __float_as_uint(f);
    u += 0x7FFFu + ((u >> 16) & 1u);
    return (short)(u >> 16);
}

// ---- y = x @ W via MFMA bf16.  Wave: 16 rows x 64 cols; block: 32 rows x 128 cols.
__global__ __launch_bounds__(256)
void gemm_mfma(const float* __restrict__ x, const float* __restrict__ W,
               unsigned short* __restrict__ y, int nrows) {
    const int lane = threadIdx.x & 63;
    const int wid  = threadIdx.x >> 6;         // 0..3
    const int colHalf = wid & 1;               // cols 0-63 / 64-127
    const int rowSub  = wid >> 1;              // row sub-tile 0/1
    const int l15 = lane & 15;
    const int lhi = lane >> 4;

    short8v bfrag[4][4];
    #pragma unroll
    for (int ks = 0; ks < 4; ++ks)
      #pragma unroll
      for (int ct = 0; ct < 4; ++ct) {
        const int col = colHalf * 64 + ct * 16 + l15;
        const int kb  = ks * 32 + lhi * 8;
        short8v f;
        #pragma unroll
        for (int j = 0; j < 8; ++j) f[j] = f2bf(W[(kb + j) * FDIM + col]);
        bfrag[ks][ct] = f;
      }

    const int nTiles = (nrows + 31) >> 5;
    for (int tile = blockIdx.x; tile < nTiles; tile += gridDim.x) {
        const int rowBase = tile * 32 + rowSub * 16;
        int arow = rowBase + l15;
        if (arow >= nrows) arow = nrows - 1;   // clamp: duplicate reads, stores guarded
        const float* xr = x + (size_t)arow * FDIM;
        f32x4 acc[4] = {};
        #pragma unroll
        for (int ks = 0; ks < 4; ++ks) {
            const int kb = ks * 32 + lhi * 8;
            float4 xa = *(const float4*)&xr[kb];
            float4 xb = *(const float4*)&xr[kb + 4];
            short8v af;
            af[0] = f2bf(xa.x); af[1] = f2bf(xa.y); af[2] = f2bf(xa.z); af[3] = f2bf(xa.w);
            af[4] = f2bf(xb.x); af[5] = f2bf(xb.y); af[6] = f2bf(xb.z); af[7] = f2bf(xb.w);
            #pragma unroll
            for (int ct = 0; ct < 4; ++ct)
                acc[ct] = __builtin_amdgcn_mfma_f32_16x16x32_bf16(af, bfrag[ks][ct], acc[ct], 0, 0, 0);
        }
        #pragma unroll
        for (int ct = 0; ct < 4; ++ct) {
            const int col = colHalf * 64 + ct * 16 + l15;
            #pragma unroll
            for (int r = 0; r < 4; ++r) {
                int orow = rowBase + lhi * 4 + r;
                if (orow < nrows) y[(size_t)orow * FDIM + col] = (unsigned short)f2bf(acc[ct][r]);
            }
        }
    }
}

// ---- counting-sort pipeline ------------------------------------------------

__global__ __launch_bounds__(256)
void edge_histogram(const int* __restrict__ row, int* __restrict__ counts, int E) {
    int i = blockIdx.x * 256 + threadIdx.x;
    if (i < E) atomicAdd(&counts[row[i]], 1);
}

// Single-workgroup scan v2: coalesced int4 tiles + shfl wave-scan (round-7, proven).
__global__ __launch_bounds__(1024)
void scan_counts_v2(const int* __restrict__ counts, int* __restrict__ offsets,
                    int* __restrict__ cursor, int n) {
    const int tid  = threadIdx.x;
    const int lane = tid & 63;
    const int wv   = tid >> 6;                  // 0..15
    __shared__ int waveSum[16];
    int carry = 0;
    const int nTiles = (n + 4095) >> 12;
    for (int tile = 0; tile < nTiles; ++tile) {
        const int idx = tile * 4096 + tid * 4;
        int4 v = make_int4(0, 0, 0, 0);
        if (idx + 3 < n) v = *(const int4*)&counts[idx];
        else if (idx < n) {
            v.x = counts[idx];
            if (idx + 1 < n) v.y = counts[idx + 1];
            if (idx + 2 < n) v.z = counts[idx + 2];
        }
        int s4 = v.x + v.y + v.z + v.w;
        int s = s4;
        #pragma unroll
        for (int off = 1; off < 64; off <<= 1) {
            int t = __shfl_up(s, off, 64);
            if (lane >= off) s += t;
        }
        if (lane == 63) waveSum[wv] = s;
        __syncthreads();
        if (tid < 64) {
            int ws = (tid < 16) ? waveSum[tid] : 0;
            #pragma unroll
            for (int off = 1; off < 16; off <<= 1) {
                int t = __shfl_up(ws, off, 64);
                if (lane >= off) ws += t;
            }
            if (tid < 16) waveSum[tid] = ws;
        }
        __syncthreads();
        const int waveBase = (wv == 0) ? 0 : waveSum[wv - 1];
        const int tileTot  = waveSum[15];
        int incl = s + waveBase + carry;
        int e0 = incl - s4;
        int4 o = make_int4(e0, e0 + v.x, e0 + v.x + v.y, e0 + v.x + v.y + v.z);
        if (idx + 3 < n) {
            *(int4*)&offsets[idx] = o;
            *(int4*)&cursor[idx]  = o;
        } else if (idx < n) {
            offsets[idx] = o.x;  cursor[idx] = o.x;
            if (idx + 1 < n) { offsets[idx + 1] = o.y; cursor[idx + 1] = o.y; }
            if (idx + 2 < n) { offsets[idx + 2] = o.z; cursor[idx + 2] = o.z; }
        }
        carry += tileTot;
        __syncthreads();
    }
    if (tid == 0) offsets[n] = carry;             // = E
}

// Chunked XCD-affine scatter + non-temporal input reads: the row/col/vals
// streams are marked nt so they don't evict partially-filled skv lines from
// the XCD L2 -> skv lines accumulate all 8 slots and evict as full lines.
__global__ __launch_bounds__(256)
void edge_scatter_chunked(const int* __restrict__ row, const int* __restrict__ col,
                          const float* __restrict__ vals, int* __restrict__ cursor,
                          int2* __restrict__ skv, int E, int rowsPerChunk) {
    const int chunk = blockIdx.x & 7;
    const int sub   = blockIdx.x >> 3;
    const int nsub  = gridDim.x >> 3;
    const int lo = chunk * rowsPerChunk;
    const int hi = lo + rowsPerChunk;
    for (int i = sub * 256 + threadIdx.x; i < E; i += nsub * 256) {
        int r = __builtin_nontemporal_load(&row[i]);
        if (r >= lo && r < hi) {
            int pos = atomicAdd(&cursor[r], 1);
            int c   = __builtin_nontemporal_load(&col[i]);
            float v = __builtin_nontemporal_load(&vals[i]);
            skv[pos] = make_int2(c, __float_as_int(v));
        }
    }
}

// ---- spmm v2: 16 lanes/edge, 4 edges per load instr, 8 edges in flight -----
__global__ __launch_bounds__(256)
void spmm_csr_v2(const int* __restrict__ offsets, const int2* __restrict__ skv,
                 const unsigned* __restrict__ yu, float* __restrict__ out, int N) {
    const int wid  = (blockIdx.x * 256 + threadIdx.x) >> 6;   // row
    const int lane = threadIdx.x & 63;
    if (wid >= N) return;
    const int l15 = lane & 15;
    const int grp = lane >> 4;           // 0..3
    const int s = offsets[wid], t = offsets[wid + 1];

    float accA[8] = {0,0,0,0,0,0,0,0};
    float accB[8] = {0,0,0,0,0,0,0,0};

    int e = s;
    for (; e + 8 <= t; e += 8) {
        int2 kA = skv[e + grp];
        int2 kB = skv[e + 4 + grp];
        uint4v uA = *(const uint4v*)&yu[(size_t)kA.x * 64 + l15 * 4];
        uint4v uB = *(const uint4v*)&yu[(size_t)kB.x * 64 + l15 * 4];
        float vA = __int_as_float(kA.y);
        float vB = __int_as_float(kB.y);
        #pragma unroll
        for (int j = 0; j < 4; ++j) {
            accA[2*j]   = fmaf(vA, __uint_as_float(uA[j] << 16),          accA[2*j]);
            accA[2*j+1] = fmaf(vA, __uint_as_float(uA[j] & 0xffff0000u), accA[2*j+1]);
            accB[2*j]   = fmaf(vB, __uint_as_float(uB[j] << 16),          accB[2*j]);
            accB[2*j+1] = fmaf(vB, __uint_as_float(uB[j] & 0xffff0000u), accB[2*j+1]);
        }
    }
    for (; e < t; e += 4) {                       // tail, predicated
        int eA = e + grp;
        bool ok = eA < t;
        int2 kA = ok ? skv[eA] : make_int2(0, 0);
        uint4v uA = *(const uint4v*)&yu[(size_t)kA.x * 64 + l15 * 4];
        float vA = ok ? __int_as_float(kA.y) : 0.f;
        #pragma unroll
        for (int j = 0; j < 4; ++j) {
            accA[2*j]   = fmaf(vA, __uint_as_float(uA[j] << 16),          accA[2*j]);
            accA[2*j+1] = fmaf(vA, __uint_as_float(uA[j] & 0xffff0000u), accA[2*j+1]);
        }
    }
    #pragma unroll
    for (int j = 0; j < 8; ++j) {
        float a = accA[j] + accB[j];
        a += __shfl_xor(a, 16, 64);
        a += __shfl_xor(a, 32, 64);
        accA[j] = a;
    }
    if (grp == 0) {
        float* po = out + (size_t)wid * FDIM + l15 * 8;
        *(float4*)po       = make_float4(accA[0], accA[1], accA[2], accA[3]);
        *(float4*)(po + 4) = make_float4(accA[4], accA[5], accA[6], accA[7]);
    }
}

// ---- fallbacks (round-1 path, never taken when ws is large enough) ---------

__global__ __launch_bounds__(256)
void gemm_rows(const float* src, const float* __restrict__ W, float* dst, int nrows) {
    __shared__ float sW[FDIM * FDIM];
    for (int i = threadIdx.x; i < FDIM * FDIM; i += 256) sW[i] = W[i];
    __syncthreads();
    const int lane = threadIdx.x & 63;
    const int wid  = (blockIdx.x * 256 + threadIdx.x) >> 6;
    const int nw   = (gridDim.x * 256) >> 6;
    for (int n = wid; n < nrows; n += nw) {
        const float* xr = src + (size_t)n * FDIM;
        float acc0 = 0.f, acc1 = 0.f;
        #pragma unroll 8
        for (int k = 0; k < FDIM; ++k) {
            float xv = xr[k];
            float2 w = *(const float2*)&sW[k * FDIM + lane * 2];
            acc0 = fmaf(xv, w.x, acc0);
            acc1 = fmaf(xv, w.y, acc1);
        }
        *(float2*)&dst[(size_t)n * FDIM + lane * 2] = make_float2(acc0, acc1);
    }
}

__global__ __launch_bounds__(256)
void spmm_scatter(const int* __restrict__ row, const int* __restrict__ col,
                  const float* __restrict__ vals, const float* __restrict__ y,
                  float* __restrict__ out, int E) {
    long long tid = (long long)blockIdx.x * 256 + threadIdx.x;
    int e = (int)(tid >> 5);
    if (e >= E) return;
    int c = ((int)tid & 31) << 2;
    int r  = row[e];
    int cl = col[e];
    float v = vals[e];
    float4 yv = *(const float4*)&y[(size_t)cl * FDIM + c];
    float* po = out + (size_t)r * FDIM + c;
    unsafeAtomicAdd(po + 0, v * yv.x);
    unsafeAtomicAdd(po + 1, v * yv.y);
    unsafeAtomicAdd(po + 2, v * yv.z);
    unsafeAtomicAdd(po + 3, v * yv.w);
}

extern "C" void kernel_launch(void* const* d_in, const int* in_sizes, int n_in,
                              void* d_out, int out_size, void* d_ws, size_t ws_size,
                              hipStream_t stream) {
    const int*   row  = (const int*)d_in[0];
    const int*   col  = (const int*)d_in[1];
    const float* vals = (const float*)d_in[2];
    const float* x    = (const float*)d_in[3];
    const float* W    = (const float*)d_in[4];
    float* out = (float*)d_out;

    const int E = in_sizes[0];
    const int N = in_sizes[3] / FDIM;

    // workspace layout (fast path); all offsets 16B-aligned for N=100000.
    char* p = (char*)d_ws;
    unsigned short* yb = (unsigned short*)p;  p += (size_t)N * FDIM * 2;   // y bf16
    int*   counts   = (int*)p;   p += (size_t)N * 4;
    int*   offsets  = (int*)p;   p += (size_t)(N + 1) * 4 + 12;
    int*   cursor   = (int*)p;   p += (size_t)N * 4;
    int2*  skv      = (int2*)p;  p += (size_t)E * 8;
    const size_t need_fast = (size_t)(p - (char*)d_ws);

    const int eb = (E + 255) / 256;
    const int rowsPerChunk = (N + 7) / 8;

    if (ws_size >= need_fast) {
        hipMemsetAsync(counts, 0, (size_t)N * 4, stream);
        gemm_mfma<<<512, 256, 0, stream>>>(x, W, yb, N);
        edge_histogram<<<eb, 256, 0, stream>>>(row, counts, E);
        scan_counts_v2<<<1, 1024, 0, stream>>>(counts, offsets, cursor, N);
        edge_scatter_chunked<<<2048, 256, 0, stream>>>(row, col, vals, cursor, skv, E, rowsPerChunk);
        spmm_csr_v2<<<((size_t)N * 64 + 255) / 256, 256, 0, stream>>>(offsets, skv, (const unsigned*)yb, out, N);
    } else if (ws_size >= (size_t)N * FDIM * 4) {
        float* yw = (float*)d_ws;
        hipMemsetAsync(d_out, 0, (size_t)out_size * sizeof(float), stream);
        gemm_rows<<<1024, 256, 0, stream>>>(x, W, yw, N);
        spmm_scatter<<<(E + 7) / 8, 256, 0, stream>>>(row, col, vals, yw, out, E);
    } else {
        hipMemsetAsync(d_out, 0, (size_t)out_size * sizeof(float), stream);
        spmm_scatter<<<(E + 7) / 8, 256, 0, stream>>>(row, col, vals, x, out, E);
        gemm_rows<<<1024, 256, 0, stream>>>(out, W, out, N);
    }
}

// Round 10
// 437.700 us; speedup vs baseline: 1.0122x; 1.0122x over previous
//
#include <hip/hip_runtime.h>
#include <hip/hip_bf16.h>

#define FDIM 128
#define NBMAX 64          // max buckets (row>>11, N <= 131072)

typedef __attribute__((ext_vector_type(8))) short short8v;   // 8 bf16 in 4 VGPRs
typedef __attribute__((ext_vector_type(4))) float f32x4;
typedef __attribute__((ext_vector_type(4))) unsigned uint4v;

__device__ __forceinline__ short f2bf(float f) {             // RNE f32 -> bf16 bits
    unsigned u = __float_as_uint(f);
    u += 0x7FFFu + ((u >> 16) & 1u);
    return (short)(u >> 16);
}

// ---- y = x @ W via MFMA bf16 (round-4, proven) ------------------------------
__global__ __launch_bounds__(256)
void gemm_mfma(const float* __restrict__ x, const float* __restrict__ W,
               unsigned short* __restrict__ y, int nrows) {
    const int lane = threadIdx.x & 63;
    const int wid  = threadIdx.x >> 6;
    const int colHalf = wid & 1;
    const int rowSub  = wid >> 1;
    const int l15 = lane & 15;
    const int lhi = lane >> 4;

    short8v bfrag[4][4];
    #pragma unroll
    for (int ks = 0; ks < 4; ++ks)
      #pragma unroll
      for (int ct = 0; ct < 4; ++ct) {
        const int col = colHalf * 64 + ct * 16 + l15;
        const int kb  = ks * 32 + lhi * 8;
        short8v f;
        #pragma unroll
        for (int j = 0; j < 8; ++j) f[j] = f2bf(W[(kb + j) * FDIM + col]);
        bfrag[ks][ct] = f;
      }

    const int nTiles = (nrows + 31) >> 5;
    for (int tile = blockIdx.x; tile < nTiles; tile += gridDim.x) {
        const int rowBase = tile * 32 + rowSub * 16;
        int arow = rowBase + l15;
        if (arow >= nrows) arow = nrows - 1;
        const float* xr = x + (size_t)arow * FDIM;
        f32x4 acc[4] = {};
        #pragma unroll
        for (int ks = 0; ks < 4; ++ks) {
            const int kb = ks * 32 + lhi * 8;
            float4 xa = *(const float4*)&xr[kb];
            float4 xb = *(const float4*)&xr[kb + 4];
            short8v af;
            af[0] = f2bf(xa.x); af[1] = f2bf(xa.y); af[2] = f2bf(xa.z); af[3] = f2bf(xa.w);
            af[4] = f2bf(xb.x); af[5] = f2bf(xb.y); af[6] = f2bf(xb.z); af[7] = f2bf(xb.w);
            #pragma unroll
            for (int ct = 0; ct < 4; ++ct)
                acc[ct] = __builtin_amdgcn_mfma_f32_16x16x32_bf16(af, bfrag[ks][ct], acc[ct], 0, 0, 0);
        }
        #pragma unroll
        for (int ct = 0; ct < 4; ++ct) {
            const int col = colHalf * 64 + ct * 16 + l15;
            #pragma unroll
            for (int r = 0; r < 4; ++r) {
                int orow = rowBase + lhi * 4 + r;
                if (orow < nrows) y[(size_t)orow * FDIM + col] = (unsigned short)f2bf(acc[ct][r]);
            }
        }
    }
}

// ---- B1: merged row-histogram + per-(block,bucket) counts -------------------
__global__ __launch_bounds__(256)
void hist_bucket(const int* __restrict__ row, int* __restrict__ counts,
                 int* __restrict__ bc, int E, int per, int B, int NB) {
    __shared__ int lc[NBMAX];
    const int blk = blockIdx.x;
    for (int b = threadIdx.x; b < NB; b += 256) lc[b] = 0;
    __syncthreads();
    const int lo = blk * per;
    const int hi = (lo + per < E) ? lo + per : E;
    for (int i = lo + threadIdx.x; i < hi; i += 256) {
        int r = row[i];
        atomicAdd(&counts[r], 1);
        atomicAdd(&lc[r >> 11], 1);
    }
    __syncthreads();
    for (int b = threadIdx.x; b < NB; b += 256) bc[b * B + blk] = lc[b];
}

// ---- single-workgroup scan (round-7, proven) --------------------------------
__global__ __launch_bounds__(1024)
void scan_counts_v2(const int* __restrict__ counts, int* __restrict__ offsets,
                    int* __restrict__ cursor, int n) {
    const int tid  = threadIdx.x;
    const int lane = tid & 63;
    const int wv   = tid >> 6;
    __shared__ int waveSum[16];
    int carry = 0;
    const int nTiles = (n + 4095) >> 12;
    for (int tile = 0; tile < nTiles; ++tile) {
        const int idx = tile * 4096 + tid * 4;
        int4 v = make_int4(0, 0, 0, 0);
        if (idx + 3 < n) v = *(const int4*)&counts[idx];
        else if (idx < n) {
            v.x = counts[idx];
            if (idx + 1 < n) v.y = counts[idx + 1];
            if (idx + 2 < n) v.z = counts[idx + 2];
        }
        int s4 = v.x + v.y + v.z + v.w;
        int s = s4;
        #pragma unroll
        for (int off = 1; off < 64; off <<= 1) {
            int t = __shfl_up(s, off, 64);
            if (lane >= off) s += t;
        }
        if (lane == 63) waveSum[wv] = s;
        __syncthreads();
        if (tid < 64) {
            int ws = (tid < 16) ? waveSum[tid] : 0;
            #pragma unroll
            for (int off = 1; off < 16; off <<= 1) {
                int t = __shfl_up(ws, off, 64);
                if (lane >= off) ws += t;
            }
            if (tid < 16) waveSum[tid] = ws;
        }
        __syncthreads();
        const int waveBase = (wv == 0) ? 0 : waveSum[wv - 1];
        const int tileTot  = waveSum[15];
        int incl = s + waveBase + carry;
        int e0 = incl - s4;
        int4 o = make_int4(e0, e0 + v.x, e0 + v.x + v.y, e0 + v.x + v.y + v.z);
        if (idx + 3 < n) {
            *(int4*)&offsets[idx] = o;
            *(int4*)&cursor[idx]  = o;
        } else if (idx < n) {
            offsets[idx] = o.x;  cursor[idx] = o.x;
            if (idx + 1 < n) { offsets[idx + 1] = o.y; cursor[idx + 1] = o.y; }
            if (idx + 2 < n) { offsets[idx + 2] = o.z; cursor[idx + 2] = o.z; }
        }
        carry += tileTot;
        __syncthreads();
    }
    if (tid == 0) offsets[n] = carry;
}

// ---- B3: bucket-grouped scatter.  Each block writes NB contiguous runs. ----
// skv1[pos] = (col | rowLocal<<17, val);  pos = bcOff[b*B+blk] + local index.
__global__ __launch_bounds__(256)
void bucket_scatter(const int* __restrict__ row, const int* __restrict__ col,
                    const float* __restrict__ vals, const int* __restrict__ bcOff,
                    int2* __restrict__ skv1, int E, int per, int B, int NB) {
    __shared__ int base[NBMAX];
    const int blk = blockIdx.x;
    for (int b = threadIdx.x; b < NB; b += 256) base[b] = bcOff[b * B + blk];
    __syncthreads();
    const int lo = blk * per;
    const int hi = (lo + per < E) ? lo + per : E;
    for (int i = lo + threadIdx.x; i < hi; i += 256) {
        int r = row[i];
        int b = r >> 11;
        int pos = atomicAdd(&base[b], 1);
        skv1[pos] = make_int2(col[i] | ((r & 2047) << 17), __float_as_int(vals[i]));
    }
}

// ---- B4: exact scatter within bucket windows (time-compressed writes). -----
// grid = 16*64; b = blockIdx&63 (XCD = b%8), sub = blockIdx>>6.
__global__ __launch_bounds__(256)
void final_scatter(const int2* __restrict__ skv1, const int* __restrict__ bcOff,
                   int* __restrict__ cursor, int2* __restrict__ skv2,
                   int E, int B, int NB) {
    const int b = blockIdx.x & 63;
    if (b >= NB) return;
    const int sub   = blockIdx.x >> 6;          // 0..15
    const int start = bcOff[b * B];
    const int end   = (b == NB - 1) ? E : bcOff[(b + 1) * B];
    const int rbase = b << 11;
    for (int i = start + sub * 256 + threadIdx.x; i < end; i += 16 * 256) {
        int2 kv = skv1[i];
        unsigned key = (unsigned)kv.x;
        int r = rbase + (int)(key >> 17);
        int pos = atomicAdd(&cursor[r], 1);
        skv2[pos] = make_int2((int)(key & 0x1FFFFu), kv.y);
    }
}

// ---- tier-B scatter (round-8, proven) ---------------------------------------
__global__ __launch_bounds__(256)
void edge_scatter_chunked(const int* __restrict__ row, const int* __restrict__ col,
                          const float* __restrict__ vals, int* __restrict__ cursor,
                          int2* __restrict__ skv, int E, int rowsPerChunk) {
    const int chunk = blockIdx.x & 7;
    const int sub   = blockIdx.x >> 3;
    const int nsub  = gridDim.x >> 3;
    const int lo = chunk * rowsPerChunk;
    const int hi = lo + rowsPerChunk;
    for (int i = sub * 256 + threadIdx.x; i < E; i += nsub * 256) {
        int r = row[i];
        if (r >= lo && r < hi) {
            int pos = atomicAdd(&cursor[r], 1);
            skv[pos] = make_int2(col[i], __float_as_int(vals[i]));
        }
    }
}

// ---- spmm v2 (round-8, proven): 16 lanes/edge, 8 edges in flight ------------
__global__ __launch_bounds__(256)
void spmm_csr_v2(const int* __restrict__ offsets, const int2* __restrict__ skv,
                 const unsigned* __restrict__ yu, float* __restrict__ out, int N) {
    const int wid  = (blockIdx.x * 256 + threadIdx.x) >> 6;
    const int lane = threadIdx.x & 63;
    if (wid >= N) return;
    const int l15 = lane & 15;
    const int grp = lane >> 4;
    const int s = offsets[wid], t = offsets[wid + 1];

    float accA[8] = {0,0,0,0,0,0,0,0};
    float accB[8] = {0,0,0,0,0,0,0,0};

    int e = s;
    for (; e + 8 <= t; e += 8) {
        int2 kA = skv[e + grp];
        int2 kB = skv[e + 4 + grp];
        uint4v uA = *(const uint4v*)&yu[(size_t)kA.x * 64 + l15 * 4];
        uint4v uB = *(const uint4v*)&yu[(size_t)kB.x * 64 + l15 * 4];
        float vA = __int_as_float(kA.y);
        float vB = __int_as_float(kB.y);
        #pragma unroll
        for (int j = 0; j < 4; ++j) {
            accA[2*j]   = fmaf(vA, __uint_as_float(uA[j] << 16),          accA[2*j]);
            accA[2*j+1] = fmaf(vA, __uint_as_float(uA[j] & 0xffff0000u), accA[2*j+1]);
            accB[2*j]   = fmaf(vB, __uint_as_float(uB[j] << 16),          accB[2*j]);
            accB[2*j+1] = fmaf(vB, __uint_as_float(uB[j] & 0xffff0000u), accB[2*j+1]);
        }
    }
    for (; e < t; e += 4) {
        int eA = e + grp;
        bool ok = eA < t;
        int2 kA = ok ? skv[eA] : make_int2(0, 0);
        uint4v uA = *(const uint4v*)&yu[(size_t)kA.x * 64 + l15 * 4];
        float vA = ok ? __int_as_float(kA.y) : 0.f;
        #pragma unroll
        for (int j = 0; j < 4; ++j) {
            accA[2*j]   = fmaf(vA, __uint_as_float(uA[j] << 16),          accA[2*j]);
            accA[2*j+1] = fmaf(vA, __uint_as_float(uA[j] & 0xffff0000u), accA[2*j+1]);
        }
    }
    #pragma unroll
    for (int j = 0; j < 8; ++j) {
        float a = accA[j] + accB[j];
        a += __shfl_xor(a, 16, 64);
        a += __shfl_xor(a, 32, 64);
        accA[j] = a;
    }
    if (grp == 0) {
        float* po = out + (size_t)wid * FDIM + l15 * 8;
        *(float4*)po       = make_float4(accA[0], accA[1], accA[2], accA[3]);
        *(float4*)(po + 4) = make_float4(accA[4], accA[5], accA[6], accA[7]);
    }
}

// ---- last-resort fallbacks (round-1) ----------------------------------------
__global__ __launch_bounds__(256)
void gemm_rows(const float* src, const float* __restrict__ W, float* dst, int nrows) {
    __shared__ float sW[FDIM * FDIM];
    for (int i = threadIdx.x; i < FDIM * FDIM; i += 256) sW[i] = W[i];
    __syncthreads();
    const int lane = threadIdx.x & 63;
    const int wid  = (blockIdx.x * 256 + threadIdx.x) >> 6;
    const int nw   = (gridDim.x * 256) >> 6;
    for (int n = wid; n < nrows; n += nw) {
        const float* xr = src + (size_t)n * FDIM;
        float acc0 = 0.f, acc1 = 0.f;
        #pragma unroll 8
        for (int k = 0; k < FDIM; ++k) {
            float xv = xr[k];
            float2 w = *(const float2*)&sW[k * FDIM + lane * 2];
            acc0 = fmaf(xv, w.x, acc0);
            acc1 = fmaf(xv, w.y, acc1);
        }
        *(float2*)&dst[(size_t)n * FDIM + lane * 2] = make_float2(acc0, acc1);
    }
}

__global__ __launch_bounds__(256)
void spmm_scatter(const int* __restrict__ row, const int* __restrict__ col,
                  const float* __restrict__ vals, const float* __restrict__ y,
                  float* __restrict__ out, int E) {
    long long tid = (long long)blockIdx.x * 256 + threadIdx.x;
    int e = (int)(tid >> 5);
    if (e >= E) return;
    int c = ((int)tid & 31) << 2;
    int r  = row[e];
    int cl = col[e];
    float v = vals[e];
    float4 yv = *(const float4*)&y[(size_t)cl * FDIM + c];
    float* po = out + (size_t)r * FDIM + c;
    unsafeAtomicAdd(po + 0, v * yv.x);
    unsafeAtomicAdd(po + 1, v * yv.y);
    unsafeAtomicAdd(po + 2, v * yv.z);
    unsafeAtomicAdd(po + 3, v * yv.w);
}

extern "C" void kernel_launch(void* const* d_in, const int* in_sizes, int n_in,
                              void* d_out, int out_size, void* d_ws, size_t ws_size,
                              hipStream_t stream) {
    const int*   row  = (const int*)d_in[0];
    const int*   col  = (const int*)d_in[1];
    const float* vals = (const float*)d_in[2];
    const float* x    = (const float*)d_in[3];
    const float* W    = (const float*)d_in[4];
    float* out = (float*)d_out;

    const int E = in_sizes[0];
    const int N = in_sizes[3] / FDIM;

    const int B  = 512;                        // histogram/scatter blocks
    const int per = (E + B - 1) / B;
    const int NB = (N + 2047) >> 11;           // row buckets (<= 64 for N <= 131072)
    const int nBC = NB * B;

    // workspace layout (tier A); every section size is a multiple of 16 B.
    char* p = (char*)d_ws;
    unsigned short* yb = (unsigned short*)p;  p += (size_t)N * FDIM * 2;
    int*   counts   = (int*)p;   p += (size_t)N * 4;
    int*   offsets  = (int*)p;   p += (size_t)(N + 1) * 4 + 12;
    int*   cursor   = (int*)p;   p += (size_t)N * 4;
    int*   bc       = (int*)p;   p += (size_t)nBC * 4;
    int*   bcOff    = (int*)p;   p += (size_t)(nBC + 1) * 4 + 12;
    int2*  skv1     = (int2*)p;  p += (size_t)E * 8;
    int2*  skv2     = (int2*)p;  p += (size_t)E * 8;
    const size_t needA = (size_t)(p - (char*)d_ws);
    const size_t needB = needA - (size_t)E * 8 - (size_t)(nBC * 4 + (nBC + 1) * 4 + 12);

    const int eb = (E + 255) / 256;
    const int rowsPerChunk = (N + 7) / 8;

    if (ws_size >= needA && N <= 131072) {
        // Tier A: two-level bucket sort -> time-local scatter writes.
        hipMemsetAsync(counts, 0, (size_t)N * 4, stream);
        gemm_mfma<<<512, 256, 0, stream>>>(x, W, yb, N);
        hist_bucket<<<B, 256, 0, stream>>>(row, counts, bc, E, per, B, NB);
        scan_counts_v2<<<1, 1024, 0, stream>>>(counts, offsets, cursor, N);
        scan_counts_v2<<<1, 1024, 0, stream>>>(bc, bcOff, bcOff, nBC);
        bucket_scatter<<<B, 256, 0, stream>>>(row, col, vals, bcOff, skv1, E, per, B, NB);
        final_scatter<<<16 * 64, 256, 0, stream>>>(skv1, bcOff, cursor, skv2, E, B, NB);
        spmm_csr_v2<<<((size_t)N * 64 + 255) / 256, 256, 0, stream>>>(offsets, skv2, (const unsigned*)yb, out, N);
    } else if (ws_size >= needB) {
        // Tier B: round-8 pipeline (single-level chunked scatter).
        int2* skv = skv1;
        hipMemsetAsync(counts, 0, (size_t)N * 4, stream);
        gemm_mfma<<<512, 256, 0, stream>>>(x, W, yb, N);
        hist_bucket<<<B, 256, 0, stream>>>(row, counts, bc, E, per, B, NB > NBMAX ? NBMAX : NB);
        scan_counts_v2<<<1, 1024, 0, stream>>>(counts, offsets, cursor, N);
        edge_scatter_chunked<<<2048, 256, 0, stream>>>(row, col, vals, cursor, skv, E, rowsPerChunk);
        spmm_csr_v2<<<((size_t)N * 64 + 255) / 256, 256, 0, stream>>>(offsets, skv, (const unsigned*)yb, out, N);
    } else if (ws_size >= (size_t)N * FDIM * 4) {
        float* yw = (float*)d_ws;
        hipMemsetAsync(d_out, 0, (size_t)out_size * sizeof(float), stream);
        gemm_rows<<<1024, 256, 0, stream>>>(x, W, yw, N);
        spmm_scatter<<<(E + 7) / 8, 256, 0, stream>>>(row, col, vals, yw, out, E);
    } else {
        hipMemsetAsync(d_out, 0, (size_t)out_size * sizeof(float), stream);
        spmm_scatter<<<(E + 7) / 8, 256, 0, stream>>>(row, col, vals, x, out, E);
        gemm_rows<<<1024, 256, 0, stream>>>(out, W, out, N);
    }
}